// Round 6
// baseline (280.677 us; speedup 1.0000x reference)
//
#include <hip/hip_runtime.h>
#include <hip/hip_bf16.h>
#include <math.h>

#define N_TS   19000
#define M_PAD  19072      // 596 * 32
#define ROWS   32         // rows per block
#define T_DIM  168
#define T_PAD  192        // 6 * 32
#define U_DIM  256
#define NBLK   3
#define HOR    24

using bf16 = __hip_bfloat16;
typedef short v8s __attribute__((ext_vector_type(8)));   // 8 bf16 (MFMA A/B frag)
typedef float v4f __attribute__((ext_vector_type(4)));   // MFMA C/D frag

// fast softplus: max(z,0) + log(1+exp(-|z|)) with native exp/log.
__device__ __forceinline__ float softplus_f(float z) {
    return fmaxf(z, 0.0f) + __logf(1.0f + __expf(-fabsf(z)));
}
__device__ __forceinline__ unsigned pack2bf(float a, float b) {
    __hip_bfloat162 t = __float22bfloat162_rn(make_float2(a, b));
    return *(unsigned*)&t;
}
__device__ __forceinline__ short f2bf_s(float x) {
    bf16 h = __float2bfloat16(x); return *(short*)&h;
}
__device__ __forceinline__ v8s make_v8(float4 f0, float4 f1) {
    v8s r;
    r[0] = f2bf_s(f0.x); r[1] = f2bf_s(f0.y); r[2] = f2bf_s(f0.z); r[3] = f2bf_s(f0.w);
    r[4] = f2bf_s(f1.x); r[5] = f2bf_s(f1.y); r[6] = f2bf_s(f1.z); r[7] = f2bf_s(f1.w);
    return r;
}

// ---------------------------------------------------------------------------
// Weight prep (unchanged):
//  [0,768):     Wvo[b] = Wo[b]@Wv[b] -> bf16; bvo = Wo@bv + bo (f32)
//  [768,1536):  Wl  -> bf16, K-pad 168->192
//  [1536,2304): Wl1 -> bf16
//  [2304,2880): W20 -> bf16, rows padded 168->192 (zeros)
//  [2880,2912): Wfc2 -> bf16, rows 24->32 (zeros), K-pad 168->192
// ---------------------------------------------------------------------------
__global__ __launch_bounds__(256) void wprep(
    const float* __restrict__ Wl, const float* __restrict__ Wl1,
    const float* __restrict__ Wv, const float* __restrict__ bv,
    const float* __restrict__ Wo, const float* __restrict__ bo,
    const float* __restrict__ W20, const float* __restrict__ Wfc2,
    bf16* __restrict__ Wlb, bf16* __restrict__ Wl1b, bf16* __restrict__ Wvob,
    bf16* __restrict__ W20b, bf16* __restrict__ Wfc2b, float* __restrict__ bvo)
{
    const int blk = blockIdx.x, j = threadIdx.x;
    if (blk < 768) {
        const int b = blk >> 8, n = blk & 255;
        const float* Wo_row = Wo + (size_t)(b * 256 + n) * 256;
        const float* Wv_b   = Wv + (size_t)b * 65536;
        float acc = 0.f;
        for (int t = 0; t < 256; ++t)
            acc = fmaf(Wo_row[t], Wv_b[(size_t)t * 256 + j], acc);
        Wvob[(size_t)(b * 256 + n) * 256 + j] = __float2bfloat16(acc);
        __shared__ float red[256];
        red[j] = Wo_row[j] * bv[b * 256 + j];
        __syncthreads();
        for (int s = 128; s > 0; s >>= 1) { if (j < s) red[j] += red[j + s]; __syncthreads(); }
        if (j == 0) bvo[b * 256 + n] = red[0] + bo[b * 256 + n];
    } else if (blk < 1536) {
        const int idx = blk - 768, b = idx >> 8, r = idx & 255;
        if (j < T_PAD)
            Wlb[(size_t)(b * 256 + r) * T_PAD + j] =
                __float2bfloat16(j < T_DIM ? Wl[(size_t)(b * 256 + r) * T_DIM + j] : 0.f);
    } else if (blk < 2304) {
        const int idx = blk - 1536, b = idx >> 8, r = idx & 255;
        Wl1b[(size_t)(b * 256 + r) * 256 + j] =
            __float2bfloat16(Wl1[(size_t)(b * 256 + r) * 256 + j]);
    } else if (blk < 2880) {
        const int idx = blk - 2304, b = idx / T_PAD, r = idx % T_PAD;
        W20b[(size_t)(b * T_PAD + r) * 256 + j] =
            __float2bfloat16(r < T_DIM ? W20[(size_t)(b * T_DIM + r) * 256 + j] : 0.f);
    } else {
        const int r = blk - 2880;   // 0..31
        if (j < T_PAD)
            Wfc2b[r * T_PAD + j] =
                __float2bfloat16((r < HOR && j < T_DIM) ? Wfc2[r * T_DIM + j] : 0.f);
    }
}

// x (f32, 19000x168) -> Xf (f32, padded 19072x192, zero-fill)
__global__ __launch_bounds__(256) void convert_x(
    const float* __restrict__ x, float* __restrict__ Xf)
{
    const int i = blockIdx.x * 256 + threadIdx.x;
    const int r = i / T_PAD, c = i - r * T_PAD;
    Xf[i] = (r < N_TS && c < T_DIM) ? x[(size_t)r * T_DIM + c] : 0.f;
}

// ---------------------------------------------------------------------------
// Fused network. ROWS=32 rows/block, 8 waves; wave w owns h-cols [32w,32w+32).
// Swapped MFMA: A = weight rows (global, L2-hot), B = activation rows.
// LDS h layout: elem (row,col) at byte row*512 + ((2*col) ^ ((row&7)<<4)).
// D frag: lane holds h[row=16j+(lane&15)][cols 32w+16i+4*(lane>>4)+r].
// ---------------------------------------------------------------------------
template<bool SP, bool BIAS>
__device__ __forceinline__ void epi_store(v4f acc[2][2], const float* bias,
                                          bf16* dst, int w, int r16, int kq)
{
    #pragma unroll
    for (int i = 0; i < 2; ++i) {
        float4 bb = make_float4(0.f, 0.f, 0.f, 0.f);
        if (BIAS) bb = *(const float4*)&bias[32 * w + 16 * i + 4 * kq];
        #pragma unroll
        for (int j = 0; j < 2; ++j) {
            float v0 = acc[i][j][0], v1 = acc[i][j][1], v2 = acc[i][j][2], v3 = acc[i][j][3];
            if (BIAS) { v0 += bb.x; v1 += bb.y; v2 += bb.z; v3 += bb.w; }
            if (SP) { v0 = softplus_f(v0); v1 = softplus_f(v1);
                      v2 = softplus_f(v2); v3 = softplus_f(v3); }
            const int row = 16 * j + r16;
            const int c0  = 32 * w + 16 * i + 4 * kq;
            const int off = row * 512 + ((2 * c0) ^ ((row & 7) << 4));
            *(uint2*)((char*)dst + off) = make_uint2(pack2bf(v0, v1), pack2bf(v2, v3));
        }
    }
}

template<bool SP, bool BIAS>
__device__ __forceinline__ void gemm_h2h(const bf16* __restrict__ W,
                                         const float* __restrict__ bias,
                                         const bf16* src, bf16* dst,
                                         int w, int r16, int kq)
{
    v4f acc[2][2] = {};
    #pragma unroll 2
    for (int ks = 0; ks < 8; ++ks) {
        v8s a[2], bfr[2];
        #pragma unroll
        for (int i = 0; i < 2; ++i)
            a[i] = *(const v8s*)&W[(size_t)(32 * w + 16 * i + r16) * 256 + ks * 32 + 8 * kq];
        #pragma unroll
        for (int j = 0; j < 2; ++j) {
            const int row = 16 * j + r16;
            bfr[j] = *(const v8s*)((const char*)src + row * 512 +
                                   ((ks * 64 + 16 * kq) ^ ((row & 7) << 4)));
        }
        #pragma unroll
        for (int i = 0; i < 2; ++i)
            #pragma unroll
            for (int j = 0; j < 2; ++j)
                acc[i][j] = __builtin_amdgcn_mfma_f32_16x16x32_bf16(a[i], bfr[j], acc[i][j], 0, 0, 0);
    }
    epi_store<SP, BIAS>(acc, bias, dst, w, r16, kq);
}

__global__ __launch_bounds__(512, 4) void fused_net(
    const bf16* __restrict__ Wlb, const bf16* __restrict__ Wl1b,
    const bf16* __restrict__ Wvob, const bf16* __restrict__ W20b,
    const bf16* __restrict__ Wfc2b, const float* __restrict__ bvo,
    float* __restrict__ Xf, float* __restrict__ out)
{
    __shared__ __align__(16) bf16 hA[ROWS * 256];
    __shared__ __align__(16) bf16 hB[ROWS * 256];

    const int tid  = threadIdx.x;
    const int lane = tid & 63, w = tid >> 6;       // 8 waves
    const int r16  = lane & 15, kq = lane >> 4;
    const int bm   = blockIdx.x * ROWS;

    for (int b = 0; b < NBLK; ++b) {
        // ---- GEMM1: hA = softplus(X @ Wl^T), K=192, B-frags from global f32 ----
        {
            const bf16* W = Wlb + (size_t)b * 256 * T_PAD;
            v4f acc[2][2] = {};
            #pragma unroll 2
            for (int ks = 0; ks < 6; ++ks) {
                v8s a[2], bfr[2];
                #pragma unroll
                for (int i = 0; i < 2; ++i)
                    a[i] = *(const v8s*)&W[(size_t)(32 * w + 16 * i + r16) * T_PAD + ks * 32 + 8 * kq];
                #pragma unroll
                for (int j = 0; j < 2; ++j) {
                    const float* xr = Xf + (size_t)(bm + 16 * j + r16) * T_PAD + ks * 32 + 8 * kq;
                    float4 f0 = *(const float4*)xr;
                    float4 f1 = *(const float4*)(xr + 4);
                    bfr[j] = make_v8(f0, f1);
                }
                #pragma unroll
                for (int i = 0; i < 2; ++i)
                    #pragma unroll
                    for (int j = 0; j < 2; ++j)
                        acc[i][j] = __builtin_amdgcn_mfma_f32_16x16x32_bf16(a[i], bfr[j], acc[i][j], 0, 0, 0);
            }
            epi_store<true, false>(acc, nullptr, hA, w, r16, kq);
        }
        __syncthreads();
        // ---- GEMM2: hB = softplus(hA @ Wl1^T) ----
        gemm_h2h<true, false>(Wl1b + (size_t)b * 65536, nullptr, hA, hB, w, r16, kq);
        __syncthreads();
        // ---- GEMM3: hA = hB @ Wvo^T + bvo ----
        gemm_h2h<false, true>(Wvob + (size_t)b * 65536, bvo + b * 256, hB, hA, w, r16, kq);
        __syncthreads();
        // ---- GEMM4: Xf += hA @ W20^T. 12 col-tiles: waves 0-3 take 2, 4-7 take 1 ----
        {
            const bf16* W = W20b + (size_t)b * T_PAD * 256;
            const int ti0 = (w < 4) ? 2 * w : 8 + (w - 4);
            const int nti = (w < 4) ? 2 : 1;
            v4f acc[2][2] = {};
            #pragma unroll 2
            for (int ks = 0; ks < 8; ++ks) {
                v8s a[2], bfr[2];
                #pragma unroll
                for (int i = 0; i < 2; ++i)
                    if (i < nti)
                        a[i] = *(const v8s*)&W[(size_t)((ti0 + i) * 16 + r16) * 256 + ks * 32 + 8 * kq];
                #pragma unroll
                for (int j = 0; j < 2; ++j) {
                    const int row = 16 * j + r16;
                    bfr[j] = *(const v8s*)((const char*)hA + row * 512 +
                                           ((ks * 64 + 16 * kq) ^ ((row & 7) << 4)));
                }
                #pragma unroll
                for (int i = 0; i < 2; ++i)
                    if (i < nti)
                        #pragma unroll
                        for (int j = 0; j < 2; ++j)
                            acc[i][j] = __builtin_amdgcn_mfma_f32_16x16x32_bf16(a[i], bfr[j], acc[i][j], 0, 0, 0);
            }
            #pragma unroll
            for (int i = 0; i < 2; ++i)
                if (i < nti)
                    #pragma unroll
                    for (int j = 0; j < 2; ++j) {
                        const int row = bm + 16 * j + r16;
                        const int c0  = (ti0 + i) * 16 + 4 * kq;
                        float4* p = (float4*)&Xf[(size_t)row * T_PAD + c0];
                        float4 v = *p;
                        v.x += acc[i][j][0]; v.y += acc[i][j][1];
                        v.z += acc[i][j][2]; v.w += acc[i][j][3];
                        *p = v;
                    }
        }
        __syncthreads();
    }

    // ---- fc2: out = X @ Wfc2^T (waves 0,1 handle 16 rows each) ----
    if (w < 2) {
        v4f acc0 = {}, acc1 = {};
        #pragma unroll
        for (int ks = 0; ks < 6; ++ks) {
            v8s a0 = *(const v8s*)&Wfc2b[(size_t)(r16) * T_PAD + ks * 32 + 8 * kq];
            v8s a1 = *(const v8s*)&Wfc2b[(size_t)(16 + r16) * T_PAD + ks * 32 + 8 * kq];
            const float* xr = Xf + (size_t)(bm + 16 * w + r16) * T_PAD + ks * 32 + 8 * kq;
            float4 f0 = *(const float4*)xr;
            float4 f1 = *(const float4*)(xr + 4);
            v8s xb_ = make_v8(f0, f1);
            acc0 = __builtin_amdgcn_mfma_f32_16x16x32_bf16(a0, xb_, acc0, 0, 0, 0);
            acc1 = __builtin_amdgcn_mfma_f32_16x16x32_bf16(a1, xb_, acc1, 0, 0, 0);
        }
        const int orow = bm + 16 * w + r16;
        if (orow < N_TS) {
            float4 v0 = make_float4(acc0[0], acc0[1], acc0[2], acc0[3]);
            *(float4*)&out[(size_t)orow * HOR + 4 * kq] = v0;
            if (kq < 2) {
                float4 v1 = make_float4(acc1[0], acc1[1], acc1[2], acc1[3]);
                *(float4*)&out[(size_t)orow * HOR + 16 + 4 * kq] = v1;
            }
        }
    }
}

// ---------------------------------------------------------------------------
extern "C" void kernel_launch(void* const* d_in, const int* in_sizes, int n_in,
                              void* d_out, int out_size, void* d_ws, size_t ws_size,
                              hipStream_t stream) {
    const float* x    = (const float*)d_in[0];
    const float* Wl   = (const float*)d_in[1];
    const float* Wl1  = (const float*)d_in[2];
    const float* Wv   = (const float*)d_in[7];
    const float* bv   = (const float*)d_in[8];
    const float* Wo   = (const float*)d_in[9];
    const float* bo   = (const float*)d_in[10];
    const float* W20  = (const float*)d_in[11];
    const float* Wfc2 = (const float*)d_in[12];
    float* out = (float*)d_out;

    char* p = (char*)d_ws;
    auto carve = [&](size_t bytes) { char* q = p; p += (bytes + 255) & ~(size_t)255; return q; };
    bf16*  Wlb   = (bf16*)carve((size_t)NBLK * 256 * T_PAD * 2);
    bf16*  Wl1b  = (bf16*)carve((size_t)NBLK * 256 * 256 * 2);
    bf16*  Wvob  = (bf16*)carve((size_t)NBLK * 256 * 256 * 2);
    bf16*  W20b  = (bf16*)carve((size_t)NBLK * T_PAD * 256 * 2);
    bf16*  Wfc2b = (bf16*)carve((size_t)32 * T_PAD * 2);
    float* bvo   = (float*)carve((size_t)NBLK * 256 * 4);
    float* Xf    = (float*)carve((size_t)M_PAD * T_PAD * 4);

    wprep<<<dim3(2912), dim3(256), 0, stream>>>(
        Wl, Wl1, Wv, bv, Wo, bo, W20, Wfc2, Wlb, Wl1b, Wvob, W20b, Wfc2b, bvo);
    convert_x<<<dim3((M_PAD * T_PAD) / 256), dim3(256), 0, stream>>>(x, Xf);
    fused_net<<<dim3(M_PAD / ROWS), dim3(512), 0, stream>>>(
        Wlb, Wl1b, Wvob, W20b, Wfc2b, bvo, Xf, out);
}